// Round 6
// baseline (2307.129 us; speedup 1.0000x reference)
//
#include <hip/hip_runtime.h>
#include <math.h>

#define B_   32
#define L_   512
#define D_   512
#define H_   8
#define DK_  64
#define NB_  2
#define DFF_ 256
#define NPID_ 10000
#define FC1_ 512
#define FC2_ 256

// ---------------------------------------------------------------------------
// Embedding + cosine positional encoding:
//   qe = q_embed[q] + difficult_param[q] * q_embed_diff[q]
//   x  = qe + pe ;  y = qa_embed[qa] + pe
// ---------------------------------------------------------------------------
__global__ __launch_bounds__(256) void embed_kernel(
    const int* __restrict__ prob, const int* __restrict__ corr,
    const float* __restrict__ q_embed, const float* __restrict__ qa_embed,
    const float* __restrict__ q_diff, const float* __restrict__ dparam,
    float* __restrict__ qe, float* __restrict__ x, float* __restrict__ y)
{
    int bl = blockIdx.x;            // b*L + l
    int l  = bl & (L_ - 1);
    int q  = prob[bl] + 1;
    int qa = q + corr[bl] * NPID_;
    const float* qe_r = q_embed + (size_t)q  * D_;
    const float* qd_r = q_diff  + (size_t)q  * D_;
    const float* dp_r = dparam  + (size_t)q  * D_;
    const float* qa_r = qa_embed + (size_t)qa * D_;
    size_t ooff = (size_t)bl * D_;
    const float nl = -logf(10000.0f) / (float)D_;
    for (int d = threadIdx.x; d < D_; d += 256) {
        int   i2   = d & ~1;
        float freq = expf((float)i2 * nl);
        float arg  = (float)l * freq;
        float pe   = (d & 1) ? cosf(arg) : sinf(arg);
        float qev  = qe_r[d] + dp_r[d] * qd_r[d];
        qe[ooff + d] = qev;
        x [ooff + d] = qev + pe;
        y [ooff + d] = qa_r[d] + pe;
    }
}

// ---------------------------------------------------------------------------
// fp32 GEMM: C[M,N] = (ACC ? C : 0) + A[M,K] @ W[K,N] (+bias) (+resid), opt ReLU
// 128x128 tile, BK=16, 256 threads, 8x8 micro-tile (4+4 split rows/cols).
// ---------------------------------------------------------------------------
template<bool HB, bool RELU, bool ACC, bool RES>
__global__ __launch_bounds__(256) void gemm_kernel(
    const float* __restrict__ A, const float* __restrict__ W,
    const float* __restrict__ bias, const float* __restrict__ resid,
    float* __restrict__ C, int M, int N, int K)
{
    __shared__ float As[16][132];   // [k][m], padded
    __shared__ float Bs[16][132];   // [k][n], padded

    int tid = threadIdx.x;
    int tx = tid & 15, ty = tid >> 4;
    int rowBase = blockIdx.y * 128;
    int colBase = blockIdx.x * 128;

    float acc[8][8];
#pragma unroll
    for (int i = 0; i < 8; ++i)
#pragma unroll
        for (int j = 0; j < 8; ++j) acc[i][j] = 0.f;

    int am = tid >> 2;                 // 0..63
    int ak = (tid & 3) << 2;           // 0,4,8,12
    int bk = tid >> 4;                 // 0..15
    int bn = (tid & 15) << 2;          // 0..60

    for (int k0 = 0; k0 < K; k0 += 16) {
        __syncthreads();
        float4 a0 = *(const float4*)&A[(size_t)(rowBase + am)      * K + k0 + ak];
        float4 a1 = *(const float4*)&A[(size_t)(rowBase + am + 64) * K + k0 + ak];
        float4 b0 = *(const float4*)&W[(size_t)(k0 + bk) * N + colBase + bn];
        float4 b1 = *(const float4*)&W[(size_t)(k0 + bk) * N + colBase + bn + 64];
        As[ak+0][am] = a0.x; As[ak+1][am] = a0.y; As[ak+2][am] = a0.z; As[ak+3][am] = a0.w;
        As[ak+0][am+64] = a1.x; As[ak+1][am+64] = a1.y; As[ak+2][am+64] = a1.z; As[ak+3][am+64] = a1.w;
        *(float4*)&Bs[bk][bn]      = b0;
        *(float4*)&Bs[bk][bn + 64] = b1;
        __syncthreads();

#pragma unroll
        for (int k = 0; k < 16; ++k) {
            float af[8], bf[8];
            *(float4*)&af[0] = *(const float4*)&As[k][ty*4];
            *(float4*)&af[4] = *(const float4*)&As[k][ty*4 + 64];
            *(float4*)&bf[0] = *(const float4*)&Bs[k][tx*4];
            *(float4*)&bf[4] = *(const float4*)&Bs[k][tx*4 + 64];
#pragma unroll
            for (int ri = 0; ri < 8; ++ri)
#pragma unroll
                for (int ci = 0; ci < 8; ++ci)
                    acc[ri][ci] += af[ri] * bf[ci];
        }
    }

#pragma unroll
    for (int rh = 0; rh < 2; ++rh) {
#pragma unroll
        for (int r = 0; r < 4; ++r) {
            int row = rowBase + rh*64 + ty*4 + r;
            size_t roff = (size_t)row * N;
#pragma unroll
            for (int ch = 0; ch < 2; ++ch) {
                int col = colBase + ch*64 + tx*4;
                float v0 = acc[rh*4+r][ch*4+0];
                float v1 = acc[rh*4+r][ch*4+1];
                float v2 = acc[rh*4+r][ch*4+2];
                float v3 = acc[rh*4+r][ch*4+3];
                if constexpr (ACC) {
                    float4 c = *(const float4*)&C[roff + col];
                    v0 += c.x; v1 += c.y; v2 += c.z; v3 += c.w;
                }
                if constexpr (HB) {
                    float4 bb = *(const float4*)&bias[col];
                    v0 += bb.x; v1 += bb.y; v2 += bb.z; v3 += bb.w;
                }
                if constexpr (RES) {
                    float4 rr = *(const float4*)&resid[roff + col];
                    v0 += rr.x; v1 += rr.y; v2 += rr.z; v3 += rr.w;
                }
                if constexpr (RELU) {
                    v0 = fmaxf(v0, 0.f); v1 = fmaxf(v1, 0.f);
                    v2 = fmaxf(v2, 0.f); v3 = fmaxf(v3, 0.f);
                }
                float4 ov; ov.x = v0; ov.y = v1; ov.z = v2; ov.w = v3;
                *(float4*)&C[roff + col] = ov;
            }
        }
    }
}

// ---------------------------------------------------------------------------
// LayerNorm over D=512, one wave per row.
// ---------------------------------------------------------------------------
__global__ __launch_bounds__(64) void ln_kernel(
    const float* __restrict__ in, const float* __restrict__ sc,
    const float* __restrict__ bi, float* __restrict__ out)
{
    int row = blockIdx.x, lane = threadIdx.x;
    const float* r = in + (size_t)row * D_;
    float4 v0 = *(const float4*)&r[lane*8];
    float4 v1 = *(const float4*)&r[lane*8 + 4];
    float sum = v0.x+v0.y+v0.z+v0.w + v1.x+v1.y+v1.z+v1.w;
    float ss  = v0.x*v0.x+v0.y*v0.y+v0.z*v0.z+v0.w*v0.w
              + v1.x*v1.x+v1.y*v1.y+v1.z*v1.z+v1.w*v1.w;
#pragma unroll
    for (int o = 1; o < 64; o <<= 1) {
        sum += __shfl_xor(sum, o);
        ss  += __shfl_xor(ss, o);
    }
    float mean = sum * (1.f / D_);
    float var  = ss  * (1.f / D_) - mean * mean;
    float rstd = rsqrtf(var + 1e-5f);
    float4 s0 = *(const float4*)&sc[lane*8];
    float4 s1 = *(const float4*)&sc[lane*8 + 4];
    float4 b0 = *(const float4*)&bi[lane*8];
    float4 b1 = *(const float4*)&bi[lane*8 + 4];
    float* w = out + (size_t)row * D_;
    float4 o0, o1;
    o0.x = (v0.x-mean)*rstd*s0.x + b0.x; o0.y = (v0.y-mean)*rstd*s0.y + b0.y;
    o0.z = (v0.z-mean)*rstd*s0.z + b0.z; o0.w = (v0.w-mean)*rstd*s0.w + b0.w;
    o1.x = (v1.x-mean)*rstd*s1.x + b1.x; o1.y = (v1.y-mean)*rstd*s1.y + b1.y;
    o1.z = (v1.z-mean)*rstd*s1.z + b1.z; o1.w = (v1.w-mean)*rstd*s1.w + b1.w;
    *(float4*)&w[lane*8]     = o0;
    *(float4*)&w[lane*8 + 4] = o1;
}

// ---------------------------------------------------------------------------
// Fused causal attention, q==k. One block per (b,h), 512 threads = 1 query row
// per thread. K(=Q) fully staged in LDS fp32 (128KB), V in 64-row tiles (16KB).
// Strict-lower causal mask (j < i); row 0 output = 0 (zero_pad).
// ---------------------------------------------------------------------------
__global__ __launch_bounds__(512) void attn_kernel(
    const float* __restrict__ qk, const float* __restrict__ vv,
    float* __restrict__ o)
{
    __shared__ float Ksh[L_][DK_];   // 128 KB
    __shared__ float Vsh[64][DK_];   // 16 KB
    int bh = blockIdx.x;
    int b = bh >> 3, h = bh & 7;
    const float* kbase = qk + (size_t)b * L_ * D_ + h * DK_;
    const float* vbase = vv + (size_t)b * L_ * D_ + h * DK_;
    int t = threadIdx.x;

    // stage K (== Q): 8192 float4s, 16 per thread, coalesced
#pragma unroll
    for (int c = 0; c < 16; ++c) {
        int f4 = c * 512 + t;
        int j  = f4 >> 4;
        int d4 = (f4 & 15) << 2;
        *(float4*)&Ksh[j][d4] = *(const float4*)&kbase[(size_t)j * D_ + d4];
    }
    __syncthreads();

    float q[DK_];
#pragma unroll
    for (int c = 0; c < 16; ++c) {
        float4 tq = *(const float4*)&Ksh[t][c*4];
        q[c*4+0] = tq.x * 0.125f; q[c*4+1] = tq.y * 0.125f;
        q[c*4+2] = tq.z * 0.125f; q[c*4+3] = tq.w * 0.125f;
    }
    float acc[DK_];
#pragma unroll
    for (int d = 0; d < DK_; ++d) acc[d] = 0.f;
    float m = -3.0e38f, s = 0.f;
    int i = t;

    for (int jt = 0; jt < L_; jt += 64) {
        __syncthreads();   // previous tile's compute done before overwrite
#pragma unroll
        for (int rep = 0; rep < 2; ++rep) {
            int f4 = rep * 512 + t;
            int j  = f4 >> 4;
            int d4 = (f4 & 15) << 2;
            *(float4*)&Vsh[j][d4] = *(const float4*)&vbase[(size_t)(jt + j) * D_ + d4];
        }
        __syncthreads();
        int jmax = min(i, jt + 64);
        for (int j0 = jt; j0 < jmax; j0 += 16) {
            float sc[16];
            float tmax = -3.0e38f;
#pragma unroll
            for (int jj = 0; jj < 16; ++jj) {       // fixed trip: sc stays in regs
                const float* kr = &Ksh[j0 + jj][0]; // wave-uniform -> LDS broadcast
                float d0 = 0.f, d1 = 0.f, d2 = 0.f, d3 = 0.f;
#pragma unroll
                for (int c = 0; c < 16; ++c) {
                    float4 kv = *(const float4*)&kr[c*4];
                    d0 += q[c*4+0]*kv.x; d1 += q[c*4+1]*kv.y;
                    d2 += q[c*4+2]*kv.z; d3 += q[c*4+3]*kv.w;
                }
                float sv = (d0 + d1) + (d2 + d3);
                sv = (j0 + jj < jmax) ? sv : -3.0e38f;   // mask j >= i
                sc[jj] = sv;
                tmax = fmaxf(tmax, sv);
            }
            float mnew = fmaxf(m, tmax);            // tmax finite (jj=0 valid)
            float cor  = __expf(m - mnew);          // first tile: exp(-inf)=0
            s *= cor;
#pragma unroll
            for (int d = 0; d < DK_; ++d) acc[d] *= cor;
#pragma unroll
            for (int jj = 0; jj < 16; ++jj) {
                float p = __expf(sc[jj] - mnew);    // masked -> exp(-3e38)=0
                s += p;
                const float* vr = &Vsh[j0 + jj - jt][0];
#pragma unroll
                for (int c = 0; c < 16; ++c) {
                    float4 vw = *(const float4*)&vr[c*4];
                    acc[c*4+0] += p * vw.x; acc[c*4+1] += p * vw.y;
                    acc[c*4+2] += p * vw.z; acc[c*4+3] += p * vw.w;
                }
            }
            m = mnew;
        }
    }
    float rs = (i > 0 && s > 0.f) ? (1.f / s) : 0.f;  // zero_pad row 0
    float* orow = o + ((size_t)b * L_ + i) * D_ + h * DK_;
#pragma unroll
    for (int c = 0; c < 16; ++c) {
        float4 w;
        w.x = acc[c*4+0]*rs; w.y = acc[c*4+1]*rs;
        w.z = acc[c*4+2]*rs; w.w = acc[c*4+3]*rs;
        *(float4*)&orow[c*4] = w;
    }
}

// ---------------------------------------------------------------------------
// Final logits: dot(h2[row], w3) + b3 -> sigmoid -> out (drop l==0)
// ---------------------------------------------------------------------------
__global__ __launch_bounds__(64) void head_out_kernel(
    const float* __restrict__ h2, const float* __restrict__ w3,
    const float* __restrict__ b3, float* __restrict__ out)
{
    int row = blockIdx.x, lane = threadIdx.x;
    float4 hv = *(const float4*)&h2[(size_t)row * FC2_ + lane*4];
    float4 wv = *(const float4*)&w3[lane*4];
    float d = hv.x*wv.x + hv.y*wv.y + hv.z*wv.z + hv.w*wv.w;
#pragma unroll
    for (int o = 1; o < 64; o <<= 1) d += __shfl_xor(d, o);
    if (lane == 0) {
        int l = row & (L_ - 1), b = row >> 9;
        if (l > 0) {
            float logit = d + b3[0];
            out[(size_t)b * (L_ - 1) + l - 1] = 1.f / (1.f + expf(-logit));
        }
    }
}

// ---------------------------------------------------------------------------
extern "C" void kernel_launch(void* const* d_in, const int* in_sizes, int n_in,
                              void* d_out, int out_size, void* d_ws, size_t ws_size,
                              hipStream_t stream)
{
    const int*   prob    = (const int*)d_in[0];
    const int*   corr    = (const int*)d_in[1];
    const float* q_embed = (const float*)d_in[2];
    const float* qa_emb  = (const float*)d_in[3];
    const float* q_diff  = (const float*)d_in[4];
    const float* dparam  = (const float*)d_in[5];
    const float* kw   = (const float*)d_in[6];
    const float* kb   = (const float*)d_in[7];
    const float* vw   = (const float*)d_in[8];
    const float* vb   = (const float*)d_in[9];
    const float* ow   = (const float*)d_in[10];
    const float* ob   = (const float*)d_in[11];
    const float* ln1s = (const float*)d_in[12];
    const float* ln1b = (const float*)d_in[13];
    const float* w1   = (const float*)d_in[14];
    const float* b1   = (const float*)d_in[15];
    const float* w2   = (const float*)d_in[16];
    const float* b2   = (const float*)d_in[17];
    const float* ln2s = (const float*)d_in[18];
    const float* ln2b = (const float*)d_in[19];
    const float* ow1  = (const float*)d_in[20];
    const float* ob1  = (const float*)d_in[21];
    const float* ow2  = (const float*)d_in[22];
    const float* ob2  = (const float*)d_in[23];
    const float* ow3  = (const float*)d_in[24];
    const float* ob3  = (const float*)d_in[25];
    float* out = (float*)d_out;

    const size_t SZ = (size_t)B_ * L_ * D_;     // 8.39M floats
    float* qe = (float*)d_ws;
    float* x  = qe + SZ;
    float* y  = x  + SZ;
    float* t0 = y  + SZ;
    float* t1 = t0 + SZ;
    float* t2 = t1 + SZ;
    float* t3 = t2 + SZ;                         // M x 256 (uses SZ/2)

    const int M = B_ * L_;                       // 16384
    dim3 g512(512 / 128, M / 128);
    dim3 g256(256 / 128, M / 128);

    embed_kernel<<<M, 256, 0, stream>>>(prob, corr, q_embed, qa_emb, q_diff, dparam,
                                        qe, x, y);

    for (int i = 0; i < NB_; ++i) {
        // qk = x@kw + kb   (q == k, single projection)
        gemm_kernel<true,false,false,false><<<g512, 256, 0, stream>>>(
            x, kw + (size_t)i*D_*D_, kb + i*D_, nullptr, t0, M, D_, D_);
        // v = y@vw + vb
        gemm_kernel<true,false,false,false><<<g512, 256, 0, stream>>>(
            y, vw + (size_t)i*D_*D_, vb + i*D_, nullptr, t1, M, D_, D_);
        // o = attn(qk, v)
        attn_kernel<<<B_*H_, 512, 0, stream>>>(t0, t1, t2);
        // t0 = x + o@ow + ob
        gemm_kernel<true,false,false,true><<<g512, 256, 0, stream>>>(
            t2, ow + (size_t)i*D_*D_, ob + i*D_, x, t0, M, D_, D_);
        // x = LN1(t0)
        ln_kernel<<<M, 64, 0, stream>>>(t0, ln1s + i*D_, ln1b + i*D_, x);
        // t3 = relu(x@w1 + b1)
        gemm_kernel<true,true,false,false><<<g256, 256, 0, stream>>>(
            x, w1 + (size_t)i*D_*DFF_, b1 + i*DFF_, nullptr, t3, M, DFF_, D_);
        // t2 = x + t3@w2 + b2
        gemm_kernel<true,false,false,true><<<g512, 256, 0, stream>>>(
            t3, w2 + (size_t)i*DFF_*D_, b2 + i*D_, x, t2, M, D_, DFF_);
        // x = LN2(t2)
        ln_kernel<<<M, 64, 0, stream>>>(t2, ln2s + i*D_, ln2b + i*D_, x);
    }

    // head: h1 = relu([x,qe]@ow1 + ob1) done as two GEMMs (split-K of concat)
    gemm_kernel<true,false,false,false><<<g512, 256, 0, stream>>>(
        x, ow1, ob1, nullptr, t0, M, FC1_, D_);
    gemm_kernel<false,true,true,false><<<g512, 256, 0, stream>>>(
        qe, ow1 + (size_t)D_*FC1_, nullptr, nullptr, t0, M, FC1_, D_);
    // h2 = relu(h1@ow2 + ob2)
    gemm_kernel<true,true,false,false><<<g256, 256, 0, stream>>>(
        t0, ow2, ob2, nullptr, t3, M, FC2_, FC1_);
    // logits + sigmoid + drop first position
    head_out_kernel<<<M, 64, 0, stream>>>(t3, ow3, ob3, out);
}